// Round 3
// baseline (174.335 us; speedup 1.0000x reference)
//
#include <hip/hip_runtime.h>

#define Cn 128
#define ICn 64
#define Nn 4096
#define Mn 1024

// ---------------------------------------------------------------------------
// K0: pre-pack weights (parallel, coalesced reads).
//     blocks 0..7: wpk[(c*64+ic)*2+{0,1}] = {w1[ic][c], w4[ic][c]}
//     block 8:     ucon[0..127]=u3 (W3^T wt), ucon[128]=c3, ucon[129..192]=wp
// ---------------------------------------------------------------------------
__global__ __launch_bounds__(256) void k_pre(
    const float* __restrict__ w1, const float* __restrict__ w4,
    const float* __restrict__ w3, const float* __restrict__ b3,
    const float* __restrict__ w5,
    float* __restrict__ wpk, float* __restrict__ ucon)
{
    const int blk = blockIdx.x;
    const int tid = threadIdx.x;
    if (blk < 8) {
        #pragma unroll
        for (int it = 0; it < 4; ++it) {
            int e = blk * 1024 + it * 256 + tid;   // 0..8191, c fast -> coalesced reads
            int c = e & 127, ic = e >> 7;
            float a = w1[ic * Cn + c];
            float d = w4[ic * Cn + c];
            *(float2*)&wpk[((size_t)c * 64 + ic) * 2] = make_float2(a, d);
        }
    } else {
        if (tid < 128) {
            float s = 0.f;
            for (int ic = 0; ic < 64; ++ic) s += w5[ic] * w3[ic * Cn + tid];
            ucon[tid] = s;
        } else if (tid == 128) {
            float s = 0.f;
            for (int ic = 0; ic < 64; ++ic) s += w5[ic] * b3[ic];
            ucon[128] = s;
        } else if (tid < 193) {
            ucon[129 + (tid - 129)] = w5[64 + (tid - 129)];
        }
    }
}

// ---------------------------------------------------------------------------
// K1: per (row-pair r, half-width wb): a1=W1x+b1, a4=W4x+b4 over 128c x 64px,
//     t = u3.x + c3, 2x2 maxpools -> xg rows and p.
// ---------------------------------------------------------------------------
__global__ __launch_bounds__(256) void k_conv(
    const float* __restrict__ x, const float* __restrict__ b1, const float* __restrict__ b4,
    const float* __restrict__ wpk, const float* __restrict__ ucon,
    float* __restrict__ t_o, float* __restrict__ p_o, float* __restrict__ xg_o)
{
    const int tile = blockIdx.x;   // 0..63
    const int r  = tile >> 1;      // row-pair 0..31
    const int wb = tile & 1;       // half-width 0..1
    const int b  = blockIdx.y;
    const int tid = threadIdx.x;

    __shared__ float xs[128 * 64];  // [c][lp], lp = rl*32+wl   (32 KB)
    __shared__ float wt1[64 * 64];  // [cl][ic] chunk            (16 KB)
    __shared__ float wt4[64 * 64];  //                           (16 KB)

    // ---- stage x tile (coalesced float4) ----
    for (int it = 0; it < 8; ++it) {
        int f = tid + 256 * it;        // 2048 float4s
        int c = f >> 4, rem = f & 15;
        int rl = rem >> 3, wq = rem & 7;
        const float* src = x + ((size_t)(b * Cn + c)) * Nn + (2 * r + rl) * 64 + 32 * wb + 4 * wq;
        *(float4*)&xs[c * 64 + rl * 32 + 4 * wq] = *(const float4*)src;
    }

    const int q   = tid & 15;          // pixel quad, px0 = 4q
    const int px0 = 4 * q;
    const int ic0 = (tid >> 4) * 4;    // 4 output channels

    float acc1[4][4], acc4[4][4];
    #pragma unroll
    for (int i = 0; i < 4; ++i) {
        float bb1 = b1[ic0 + i], bb4 = b4[ic0 + i];
        #pragma unroll
        for (int j = 0; j < 4; ++j) { acc1[i][j] = bb1; acc4[i][j] = bb4; }
    }

    for (int ch = 0; ch < 2; ++ch) {
        __syncthreads();   // xs ready (ch=0) / prev chunk's reads done (ch=1)
        for (int it = 0; it < 16; ++it) {
            int e = tid + 256 * it;    // 4096: ic fast -> coalesced global, bank-clean LDS
            int ic = e & 63, cl = e >> 6;
            float2 wv = *(const float2*)&wpk[(((size_t)(64 * ch + cl)) * 64 + ic) * 2];
            wt1[cl * 64 + ic] = wv.x;
            wt4[cl * 64 + ic] = wv.y;
        }
        __syncthreads();
        for (int cl = 0; cl < 64; ++cl) {
            float4 xv  = *(const float4*)&xs[(64 * ch + cl) * 64 + px0];
            float4 w1v = *(const float4*)&wt1[cl * 64 + ic0];
            float4 w4v = *(const float4*)&wt4[cl * 64 + ic0];
            float xa[4] = { xv.x, xv.y, xv.z, xv.w };
            float wa1[4] = { w1v.x, w1v.y, w1v.z, w1v.w };
            float wa4[4] = { w4v.x, w4v.y, w4v.z, w4v.w };
            #pragma unroll
            for (int i = 0; i < 4; ++i)
                #pragma unroll
                for (int j = 0; j < 4; ++j) {
                    acc1[i][j] += wa1[i] * xa[j];
                    acc4[i][j] += wa4[i] * xa[j];
                }
        }
    }
    __syncthreads();   // compute done; wt1/wt4 regions free

    float* ph = wt1;   // pool buffer [2 rl][16 pw][68]  (2176 floats)
    const int rl  = q >> 3;
    const int pw0 = (q & 7) * 2;
    #pragma unroll
    for (int i = 0; i < 4; ++i) {
        ph[(rl * 16 + pw0    ) * 68 + ic0 + i] = fmaxf(acc1[i][0], acc1[i][1]);
        ph[(rl * 16 + pw0 + 1) * 68 + ic0 + i] = fmaxf(acc1[i][2], acc1[i][3]);
    }
    __syncthreads();

    // xg rows (pool of a1)
    for (int e = tid; e < 1024; e += 256) {
        int pw = e >> 6, ic = e & 63;
        float v = fmaxf(ph[pw * 68 + ic], ph[(16 + pw) * 68 + ic]);
        xg_o[((size_t)b * Mn + r * 32 + wb * 16 + pw) * 64 + ic] = v;
    }
    // t for the 64 pixels
    if (tid < 64) {
        float s = ucon[128];
        for (int c = 0; c < 128; ++c) s += ucon[c] * xs[c * 64 + tid];
        t_o[(size_t)b * Nn + (2 * r + (tid >> 5)) * 64 + 32 * wb + (tid & 31)] = s;
    }
    __syncthreads();

    #pragma unroll
    for (int i = 0; i < 4; ++i) {
        ph[(rl * 16 + pw0    ) * 68 + ic0 + i] = fmaxf(acc4[i][0], acc4[i][1]);
        ph[(rl * 16 + pw0 + 1) * 68 + ic0 + i] = fmaxf(acc4[i][2], acc4[i][3]);
    }
    __syncthreads();
    if (tid < 16) {
        float s = 0.f;
        for (int ic = 0; ic < 64; ++ic)
            s += ucon[129 + ic] * fmaxf(ph[tid * 68 + ic], ph[(16 + tid) * 68 + ic]);
        p_o[(size_t)b * Mn + r * 32 + wb * 16 + tid] = s;
    }
}

// ---------------------------------------------------------------------------
// K2: g[b][m][co] = sum_i xg[b][m][i] * w2[co][i]   (two co-half passes)
// ---------------------------------------------------------------------------
__global__ __launch_bounds__(256) void k_g(
    const float* __restrict__ xg, const float* __restrict__ w2, float* __restrict__ g)
{
    const int mt = blockIdx.x;     // 0..7 (128-row m tiles)
    const int b  = blockIdx.y;
    const int tid = threadIdx.x;
    __shared__ float xgs[128 * 65];
    __shared__ float w2h[64 * 65];

    for (int it = 0; it < 8; ++it) {
        int f = tid + 256 * it;        // 2048 float4s
        int ml = f >> 4, i0 = (f & 15) * 4;
        float4 v = *(const float4*)&xg[((size_t)b * Mn + mt * 128 + ml) * 64 + i0];
        xgs[ml * 65 + i0 + 0] = v.x; xgs[ml * 65 + i0 + 1] = v.y;
        xgs[ml * 65 + i0 + 2] = v.z; xgs[ml * 65 + i0 + 3] = v.w;
    }

    const int ml0  = tid & 15;
    const int coL0 = (tid >> 4) * 4;

    for (int coh = 0; coh < 2; ++coh) {
        __syncthreads();
        for (int it = 0; it < 16; ++it) {
            int e = tid + 256 * it;    // 4096: i fast -> coalesced read
            int co_l = e >> 6, i = e & 63;
            w2h[i * 65 + co_l] = w2[(coh * 64 + co_l) * 64 + i];
        }
        __syncthreads();

        float acc[8][4];
        #pragma unroll
        for (int k = 0; k < 8; ++k) for (int j = 0; j < 4; ++j) acc[k][j] = 0.f;

        for (int i = 0; i < 64; ++i) {
            float xv[8];
            #pragma unroll
            for (int k = 0; k < 8; ++k) xv[k] = xgs[(ml0 + 16 * k) * 65 + i];
            float wv[4];
            #pragma unroll
            for (int j = 0; j < 4; ++j) wv[j] = w2h[i * 65 + coL0 + j];
            #pragma unroll
            for (int k = 0; k < 8; ++k)
                #pragma unroll
                for (int j = 0; j < 4; ++j) acc[k][j] += xv[k] * wv[j];
        }
        #pragma unroll
        for (int k = 0; k < 8; ++k) {
            float4 v = { acc[k][0], acc[k][1], acc[k][2], acc[k][3] };
            *(float4*)&g[((size_t)b * Mn + mt * 128 + ml0 + 16 * k) * 128 + coh * 64 + coL0] = v;
        }
    }
}

// ---------------------------------------------------------------------------
// K3: rank-by-counting sort (barrier-free). Each thread: rank of (p[m], m)
//     in lexicographic order; scatter write -> ps ascending + perm.
// ---------------------------------------------------------------------------
__global__ __launch_bounds__(128) void k_rank(
    const float* __restrict__ p, float* __restrict__ ps, int* __restrict__ perm)
{
    const int mc = blockIdx.x;     // 0..7 (128-m chunks)
    const int b  = blockIdx.y;
    const int tid = threadIdx.x;
    __shared__ float pls[1024];
    #pragma unroll
    for (int it = 0; it < 2; ++it) {
        int f = tid + 128 * it;    // 256 float4s
        *(float4*)&pls[f * 4] = *(const float4*)&p[b * 1024 + f * 4];
    }
    __syncthreads();
    const int m = mc * 128 + tid;
    const float key = pls[m];
    int rank = 0;
    #pragma unroll 8
    for (int j = 0; j < 1024; ++j) {
        float v = pls[j];                    // broadcast read — conflict-free
        rank += (v < key || (v == key && j < m)) ? 1 : 0;
    }
    ps[b * 1024 + rank]   = key;
    perm[b * 1024 + rank] = m;
}

// ---------------------------------------------------------------------------
// K4: per 32-j segment chunk sums of g_sorted and p*g_sorted
// ---------------------------------------------------------------------------
__global__ __launch_bounds__(256) void k_scanA(
    const float* __restrict__ g, const float* __restrict__ ps, const int* __restrict__ perm,
    float* __restrict__ csa, float* __restrict__ csb)
{
    const int seg = blockIdx.x;    // 0..31
    const int b = blockIdx.y;
    const int tid = threadIdx.x;
    const int co = tid & 127, jh = tid >> 7;
    __shared__ float redA[2][128], redB[2][128];
    __shared__ float pl[32];
    __shared__ int   pml[32];
    if (tid < 32) { pl[tid] = ps[b * 1024 + seg * 32 + tid]; pml[tid] = perm[b * 1024 + seg * 32 + tid]; }
    __syncthreads();
    float sA = 0.f, sB = 0.f;
    for (int jj = jh * 16; jj < jh * 16 + 16; ++jj) {
        float gv = g[((size_t)b * Mn + pml[jj]) * 128 + co];
        sA += gv; sB += pl[jj] * gv;
    }
    redA[jh][co] = sA; redB[jh][co] = sB;
    __syncthreads();
    if (tid < 128) {
        csa[(b * 32 + seg) * 128 + tid] = redA[0][tid] + redA[1][tid];
        csb[(b * 32 + seg) * 128 + tid] = redB[0][tid] + redB[1][tid];
    }
}

// ---------------------------------------------------------------------------
// K5: suffix-sum walk -> SA[b][k][co], SB[b][k][co], k in [0,1024].
//     g rows staged to LDS by all 256 threads; SA/SB walks run concurrently.
// ---------------------------------------------------------------------------
__global__ __launch_bounds__(256) void k_scanC(
    const float* __restrict__ g, const float* __restrict__ ps, const int* __restrict__ perm,
    const float* __restrict__ csa, const float* __restrict__ csb,
    float* __restrict__ SA, float* __restrict__ SB)
{
    const int seg = blockIdx.x;    // 0..31
    const int b = blockIdx.y;
    const int tid = threadIdx.x;
    __shared__ float gs[32 * 128];
    __shared__ float pl[32];
    __shared__ int   pml[32];
    if (tid < 32) { pl[tid] = ps[b * 1024 + seg * 32 + tid]; pml[tid] = perm[b * 1024 + seg * 32 + tid]; }
    __syncthreads();
    for (int it = 0; it < 16; ++it) {
        int f = tid + 256 * it;    // 4096 = 32 rows x 128 co
        int jj = f >> 7, co = f & 127;
        gs[jj * 128 + co] = g[((size_t)b * Mn + pml[jj]) * 128 + co];
    }
    __syncthreads();

    const int co = tid & 127;
    if (tid < 128) {               // SA walk
        float rA = 0.f;
        for (int s = seg + 1; s < 32; ++s) rA += csa[(b * 32 + s) * 128 + co];
        if (seg == 31) SA[((size_t)b * 1025 + 1024) * 128 + co] = 0.f;
        for (int jj = 31; jj >= 0; --jj) {
            rA += gs[jj * 128 + co];
            SA[((size_t)b * 1025 + seg * 32 + jj) * 128 + co] = rA;
        }
    } else {                       // SB walk
        float rB = 0.f;
        for (int s = seg + 1; s < 32; ++s) rB += csb[(b * 32 + s) * 128 + co];
        if (seg == 31) SB[((size_t)b * 1025 + 1024) * 128 + co] = 0.f;
        for (int jj = 31; jj >= 0; --jj) {
            rB += pl[jj] * gs[jj * 128 + co];
            SB[((size_t)b * 1025 + seg * 32 + jj) * 128 + co] = rB;
        }
    }
}

// ---------------------------------------------------------------------------
// K6: out[b][co][n] = ((t[n]*SA[k(n)][co] + SB[k(n)][co])/M)*sc[co] + bs[co] + x
// ---------------------------------------------------------------------------
__global__ __launch_bounds__(256) void k_final(
    const float* __restrict__ x, const float* __restrict__ t,
    const float* __restrict__ ps, const float* __restrict__ SA, const float* __restrict__ SB,
    const float* __restrict__ b2, const float* __restrict__ gamma, const float* __restrict__ beta,
    const float* __restrict__ mean, const float* __restrict__ var,
    float* __restrict__ out)
{
    const int nt = blockIdx.x;     // 0..31 (128-pixel n tiles)
    const int b = blockIdx.y;
    const int tid = threadIdx.x;
    const int n0 = nt * 128;
    __shared__ float psl[1024];
    __shared__ float tl[128];
    __shared__ int   kl[128];
    __shared__ float sc[128], bs[128];
    __shared__ float sa_s[32][129], sb_s[32][129];

    for (int it = 0; it < 4; ++it) psl[tid + 256 * it] = ps[b * 1024 + tid + 256 * it];
    __syncthreads();
    if (tid < 128) {
        float tv = t[(size_t)b * Nn + n0 + tid];
        tl[tid] = tv;
        float key = -tv;
        int lo = 0, hi = 1024;
        while (lo < hi) { int mid = (lo + hi) >> 1; if (psl[mid] > key) hi = mid; else lo = mid + 1; }
        kl[tid] = lo;
    } else {
        int co = tid - 128;
        float s = gamma[co] * rsqrtf(var[co] + 1e-5f);
        sc[co] = s;
        bs[co] = (b2[co] - mean[co]) * s + beta[co];
    }
    __syncthreads();

    const float invM = 1.0f / 1024.0f;
    for (int sub = 0; sub < 4; ++sub) {
        for (int it = 0; it < 16; ++it) {
            int f = tid + 256 * it;          // 4096: 32 rows x 128 co
            int rowl = f >> 7, co = f & 127;
            int k = kl[sub * 32 + rowl];
            sa_s[rowl][co] = SA[((size_t)b * 1025 + k) * 128 + co];
            sb_s[rowl][co] = SB[((size_t)b * 1025 + k) * 128 + co];
        }
        __syncthreads();
        for (int it = 0; it < 4; ++it) {
            int f = tid + 256 * it;          // 1024 float4s: 128 co x 8 n-quads
            int co = f >> 3, nn0 = (f & 7) * 4;
            size_t gidx = ((size_t)b * Cn + co) * Nn + n0 + sub * 32 + nn0;
            float4 xv = *(const float4*)&x[gidx];
            float scv = sc[co], bsv = bs[co];
            float4 o;
            float v0 = (tl[sub*32+nn0+0] * sa_s[nn0+0][co] + sb_s[nn0+0][co]) * invM;
            float v1 = (tl[sub*32+nn0+1] * sa_s[nn0+1][co] + sb_s[nn0+1][co]) * invM;
            float v2 = (tl[sub*32+nn0+2] * sa_s[nn0+2][co] + sb_s[nn0+2][co]) * invM;
            float v3 = (tl[sub*32+nn0+3] * sa_s[nn0+3][co] + sb_s[nn0+3][co]) * invM;
            o.x = v0 * scv + bsv + xv.x;
            o.y = v1 * scv + bsv + xv.y;
            o.z = v2 * scv + bsv + xv.z;
            o.w = v3 * scv + bsv + xv.w;
            *(float4*)&out[gidx] = o;
        }
        __syncthreads();
    }
}

// ---------------------------------------------------------------------------
extern "C" void kernel_launch(void* const* d_in, const int* in_sizes, int n_in,
                              void* d_out, int out_size, void* d_ws, size_t ws_size,
                              hipStream_t stream)
{
    const float* x  = (const float*)d_in[0];
    const float* w1 = (const float*)d_in[1];
    const float* b1 = (const float*)d_in[2];
    const float* w3 = (const float*)d_in[3];
    const float* b3 = (const float*)d_in[4];
    const float* w4 = (const float*)d_in[5];
    const float* b4 = (const float*)d_in[6];
    const float* w5 = (const float*)d_in[7];
    const float* w2 = (const float*)d_in[8];
    const float* b2 = (const float*)d_in[9];
    const float* gm = (const float*)d_in[10];
    const float* bt = (const float*)d_in[11];
    const float* mn = (const float*)d_in[12];
    const float* vr = (const float*)d_in[13];
    float* out = (float*)d_out;

    float* ws = (float*)d_ws;
    const size_t FTOT = 3811584;           // floats (~15.25 MB)
    if (ws_size < FTOT * sizeof(float)) return;

    float* t_w  = ws;                      // 32768
    float* p_w  = ws + 32768;              // 8192
    float* ps_w = ws + 40960;              // 8192
    int*   pm_w = (int*)(ws + 49152);      // 8192
    float* xg_w = ws + 57344;              // 524288
    float* g_w  = ws + 581632;             // 1048576
    float* csa  = ws + 1630208;            // 32768
    float* csb  = ws + 1662976;            // 32768
    float* SAp  = ws + 1695744;            // 1049600
    float* SBp  = ws + 2745344;            // 1049600
    float* wpk  = ws + 3794944;            // 16384
    float* ucon = ws + 3811328;            // 256

    k_pre  <<<9,           256, 0, stream>>>(w1, w4, w3, b3, w5, wpk, ucon);
    k_conv <<<dim3(64, 8), 256, 0, stream>>>(x, b1, b4, wpk, ucon, t_w, p_w, xg_w);
    k_g    <<<dim3(8, 8),  256, 0, stream>>>(xg_w, w2, g_w);
    k_rank <<<dim3(8, 8),  128, 0, stream>>>(p_w, ps_w, pm_w);
    k_scanA<<<dim3(32, 8), 256, 0, stream>>>(g_w, ps_w, pm_w, csa, csb);
    k_scanC<<<dim3(32, 8), 256, 0, stream>>>(g_w, ps_w, pm_w, csa, csb, SAp, SBp);
    k_final<<<dim3(32, 8), 256, 0, stream>>>(x, t_w, ps_w, SAp, SBp, b2, gm, bt, mn, vr, out);
}

// Round 4
// 160.730 us; speedup vs baseline: 1.0846x; 1.0846x over previous
//
#include <hip/hip_runtime.h>

#define Cn 128
#define ICn 64
#define Nn 4096
#define Mn 1024

// ---------------------------------------------------------------------------
// K0: pre-pack weights (parallel, coalesced reads).
//     blocks 0..7: wpk[(c*64+ic)*2+{0,1}] = {w1[ic][c], w4[ic][c]}
//     block 8:     ucon[0..127]=u3 (W3^T wt), ucon[128]=c3, ucon[129..192]=wp
// ---------------------------------------------------------------------------
__global__ __launch_bounds__(256) void k_pre(
    const float* __restrict__ w1, const float* __restrict__ w4,
    const float* __restrict__ w3, const float* __restrict__ b3,
    const float* __restrict__ w5,
    float* __restrict__ wpk, float* __restrict__ ucon)
{
    const int blk = blockIdx.x;
    const int tid = threadIdx.x;
    if (blk < 8) {
        #pragma unroll
        for (int it = 0; it < 4; ++it) {
            int e = blk * 1024 + it * 256 + tid;   // 0..8191, c fast -> coalesced reads
            int c = e & 127, ic = e >> 7;
            float a = w1[ic * Cn + c];
            float d = w4[ic * Cn + c];
            *(float2*)&wpk[((size_t)c * 64 + ic) * 2] = make_float2(a, d);
        }
    } else {
        if (tid < 128) {
            float s = 0.f;
            for (int ic = 0; ic < 64; ++ic) s += w5[ic] * w3[ic * Cn + tid];
            ucon[tid] = s;
        } else if (tid == 128) {
            float s = 0.f;
            for (int ic = 0; ic < 64; ++ic) s += w5[ic] * b3[ic];
            ucon[128] = s;
        } else if (tid < 193) {
            ucon[129 + (tid - 129)] = w5[64 + (tid - 129)];
        }
    }
}

// ---------------------------------------------------------------------------
// K1: per (row-pair r, half-width wb):
//     a1=W1x+b1, a4=W4x+b4 over 128c x 64px; t = u3.x + c3;
//     2x2 maxpool(a1) -> xgr (LDS only) -> g = xgr . W2^T  (k_g fused);
//     2x2 maxpool(a4) -> p.
// LDS partition of smem[16384] floats (64 KB):
//   phase A: xs = [0..8191] x-tile [c][lp]; wt1 = [8192..12287], wt4 = [12288..16383]
//   phase B: ph (pool halves, 2176 fl) @ 14208; xgr (16x68) @ 13056;
//            w2t (64x129, 8256 fl) @ 0 (spills 64 fl into dead wt1 -- fine)
// ---------------------------------------------------------------------------
__global__ __launch_bounds__(256) void k_conv(
    const float* __restrict__ x, const float* __restrict__ b1, const float* __restrict__ b4,
    const float* __restrict__ wpk, const float* __restrict__ ucon,
    const float* __restrict__ w2,
    float* __restrict__ t_o, float* __restrict__ p_o, float* __restrict__ g_o)
{
    const int tile = blockIdx.x;   // 0..63
    const int r  = tile >> 1;      // row-pair 0..31
    const int wb = tile & 1;       // half-width 0..1
    const int b  = blockIdx.y;
    const int tid = threadIdx.x;

    __shared__ float smem[16384];
    float* xs  = smem;             // 8192
    float* wt1 = smem + 8192;      // 4096
    float* wt4 = smem + 12288;     // 4096
    float* w2t = smem;             // 8256 (phase B)
    float* xgr = smem + 13056;     // 1088 (phase B)
    float* ph  = smem + 14208;     // 2176 (phase B)

    // ---- stage x tile (coalesced float4) ----
    for (int it = 0; it < 8; ++it) {
        int f = tid + 256 * it;        // 2048 float4s
        int c = f >> 4, rem = f & 15;
        int rl = rem >> 3, wq = rem & 7;
        const float* src = x + ((size_t)(b * Cn + c)) * Nn + (2 * r + rl) * 64 + 32 * wb + 4 * wq;
        *(float4*)&xs[c * 64 + rl * 32 + 4 * wq] = *(const float4*)src;
    }

    const int q   = tid & 15;          // pixel quad, px0 = 4q
    const int px0 = 4 * q;
    const int ic0 = (tid >> 4) * 4;    // 4 output channels

    float acc1[4][4], acc4[4][4];
    #pragma unroll
    for (int i = 0; i < 4; ++i) {
        float bb1 = b1[ic0 + i], bb4 = b4[ic0 + i];
        #pragma unroll
        for (int j = 0; j < 4; ++j) { acc1[i][j] = bb1; acc4[i][j] = bb4; }
    }

    for (int ch = 0; ch < 2; ++ch) {
        __syncthreads();   // xs ready (ch=0) / prev chunk's reads done (ch=1)
        for (int it = 0; it < 16; ++it) {
            int e = tid + 256 * it;    // 4096: ic fast -> coalesced global, bank-clean LDS
            int ic = e & 63, cl = e >> 6;
            float2 wv = *(const float2*)&wpk[(((size_t)(64 * ch + cl)) * 64 + ic) * 2];
            wt1[cl * 64 + ic] = wv.x;
            wt4[cl * 64 + ic] = wv.y;
        }
        __syncthreads();
        for (int cl = 0; cl < 64; ++cl) {
            float4 xv  = *(const float4*)&xs[(64 * ch + cl) * 64 + px0];
            float4 w1v = *(const float4*)&wt1[cl * 64 + ic0];
            float4 w4v = *(const float4*)&wt4[cl * 64 + ic0];
            float xa[4] = { xv.x, xv.y, xv.z, xv.w };
            float wa1[4] = { w1v.x, w1v.y, w1v.z, w1v.w };
            float wa4[4] = { w4v.x, w4v.y, w4v.z, w4v.w };
            #pragma unroll
            for (int i = 0; i < 4; ++i)
                #pragma unroll
                for (int j = 0; j < 4; ++j) {
                    acc1[i][j] += wa1[i] * xa[j];
                    acc4[i][j] += wa4[i] * xa[j];
                }
        }
    }
    __syncthreads();   // compute done; wt1/wt4 regions dead

    // ---- a1 pool halves -> ph ----
    const int rl  = q >> 3;
    const int pw0 = (q & 7) * 2;
    #pragma unroll
    for (int i = 0; i < 4; ++i) {
        ph[(rl * 16 + pw0    ) * 68 + ic0 + i] = fmaxf(acc1[i][0], acc1[i][1]);
        ph[(rl * 16 + pw0 + 1) * 68 + ic0 + i] = fmaxf(acc1[i][2], acc1[i][3]);
    }
    __syncthreads();

    // ---- xgr = final a1 pool (LDS); t from xs (last use of xs) ----
    for (int e = tid; e < 1024; e += 256) {
        int pw = e >> 6, ic = e & 63;
        xgr[pw * 68 + ic] = fmaxf(ph[pw * 68 + ic], ph[(16 + pw) * 68 + ic]);
    }
    if (tid < 64) {
        float s = ucon[128];
        for (int c = 0; c < 128; ++c) s += ucon[c] * xs[c * 64 + tid];
        t_o[(size_t)b * Nn + (2 * r + (tid >> 5)) * 64 + 32 * wb + (tid & 31)] = s;
    }
    __syncthreads();   // xgr ready; xs free

    // ---- stage w2 transposed into xs region; a4 pool halves -> ph ----
    for (int it = 0; it < 32; ++it) {
        int e = tid + 256 * it;        // 8192 linear: co = e>>6, ic = e&63
        int co = e >> 6, ic = e & 63;
        w2t[ic * 129 + co] = w2[e];    // banks (ic+co)%32 -> 2-way, free
    }
    #pragma unroll
    for (int i = 0; i < 4; ++i) {
        ph[(rl * 16 + pw0    ) * 68 + ic0 + i] = fmaxf(acc4[i][0], acc4[i][1]);
        ph[(rl * 16 + pw0 + 1) * 68 + ic0 + i] = fmaxf(acc4[i][2], acc4[i][3]);
    }
    __syncthreads();

    // ---- g = xgr . W2^T : thread = (co, half); 8 pw rows each ----
    {
        const int co   = tid & 127;
        const int half = tid >> 7;
        float gacc[8];
        #pragma unroll
        for (int k = 0; k < 8; ++k) gacc[k] = 0.f;
        for (int ic = 0; ic < 64; ++ic) {
            float wv = w2t[ic * 129 + co];
            #pragma unroll
            for (int k = 0; k < 8; ++k)
                gacc[k] += xgr[(half * 8 + k) * 68 + ic] * wv;
        }
        #pragma unroll
        for (int k = 0; k < 8; ++k) {
            int m = r * 32 + wb * 16 + half * 8 + k;
            g_o[((size_t)b * Mn + m) * 128 + co] = gacc[k];
        }
    }

    // ---- p from a4 pool ----
    if (tid < 16) {
        float s = 0.f;
        for (int ic = 0; ic < 64; ++ic)
            s += ucon[129 + ic] * fmaxf(ph[tid * 68 + ic], ph[(16 + tid) * 68 + ic]);
        p_o[(size_t)b * Mn + r * 32 + wb * 16 + tid] = s;
    }
}

// ---------------------------------------------------------------------------
// K3: rank-by-counting sort (barrier-free after load).
// ---------------------------------------------------------------------------
__global__ __launch_bounds__(128) void k_rank(
    const float* __restrict__ p, float* __restrict__ ps, int* __restrict__ perm)
{
    const int mc = blockIdx.x;     // 0..7 (128-m chunks)
    const int b  = blockIdx.y;
    const int tid = threadIdx.x;
    __shared__ float pls[1024];
    #pragma unroll
    for (int it = 0; it < 2; ++it) {
        int f = tid + 128 * it;    // 256 float4s
        *(float4*)&pls[f * 4] = *(const float4*)&p[b * 1024 + f * 4];
    }
    __syncthreads();
    const int m = mc * 128 + tid;
    const float key = pls[m];
    int rank = 0;
    #pragma unroll 8
    for (int j = 0; j < 1024; ++j) {
        float v = pls[j];                    // broadcast read — conflict-free
        rank += (v < key || (v == key && j < m)) ? 1 : 0;
    }
    ps[b * 1024 + rank]   = key;
    perm[b * 1024 + rank] = m;
}

// ---------------------------------------------------------------------------
// K4: per 32-j segment chunk sums of g_sorted and p*g_sorted
// ---------------------------------------------------------------------------
__global__ __launch_bounds__(256) void k_scanA(
    const float* __restrict__ g, const float* __restrict__ ps, const int* __restrict__ perm,
    float* __restrict__ csa, float* __restrict__ csb)
{
    const int seg = blockIdx.x;    // 0..31
    const int b = blockIdx.y;
    const int tid = threadIdx.x;
    const int co = tid & 127, jh = tid >> 7;
    __shared__ float redA[2][128], redB[2][128];
    __shared__ float pl[32];
    __shared__ int   pml[32];
    if (tid < 32) { pl[tid] = ps[b * 1024 + seg * 32 + tid]; pml[tid] = perm[b * 1024 + seg * 32 + tid]; }
    __syncthreads();
    float sA = 0.f, sB = 0.f;
    for (int jj = jh * 16; jj < jh * 16 + 16; ++jj) {
        float gv = g[((size_t)b * Mn + pml[jj]) * 128 + co];
        sA += gv; sB += pl[jj] * gv;
    }
    redA[jh][co] = sA; redB[jh][co] = sB;
    __syncthreads();
    if (tid < 128) {
        csa[(b * 32 + seg) * 128 + tid] = redA[0][tid] + redA[1][tid];
        csb[(b * 32 + seg) * 128 + tid] = redB[0][tid] + redB[1][tid];
    }
}

// ---------------------------------------------------------------------------
// K5: suffix-sum walk -> SA[b][k][co], SB[b][k][co], k in [0,1024].
// ---------------------------------------------------------------------------
__global__ __launch_bounds__(256) void k_scanC(
    const float* __restrict__ g, const float* __restrict__ ps, const int* __restrict__ perm,
    const float* __restrict__ csa, const float* __restrict__ csb,
    float* __restrict__ SA, float* __restrict__ SB)
{
    const int seg = blockIdx.x;    // 0..31
    const int b = blockIdx.y;
    const int tid = threadIdx.x;
    __shared__ float gs[32 * 128];
    __shared__ float pl[32];
    __shared__ int   pml[32];
    if (tid < 32) { pl[tid] = ps[b * 1024 + seg * 32 + tid]; pml[tid] = perm[b * 1024 + seg * 32 + tid]; }
    __syncthreads();
    for (int it = 0; it < 16; ++it) {
        int f = tid + 256 * it;    // 4096 = 32 rows x 128 co
        int jj = f >> 7, co = f & 127;
        gs[jj * 128 + co] = g[((size_t)b * Mn + pml[jj]) * 128 + co];
    }
    __syncthreads();

    const int co = tid & 127;
    if (tid < 128) {               // SA walk
        float rA = 0.f;
        for (int s = seg + 1; s < 32; ++s) rA += csa[(b * 32 + s) * 128 + co];
        if (seg == 31) SA[((size_t)b * 1025 + 1024) * 128 + co] = 0.f;
        for (int jj = 31; jj >= 0; --jj) {
            rA += gs[jj * 128 + co];
            SA[((size_t)b * 1025 + seg * 32 + jj) * 128 + co] = rA;
        }
    } else {                       // SB walk
        float rB = 0.f;
        for (int s = seg + 1; s < 32; ++s) rB += csb[(b * 32 + s) * 128 + co];
        if (seg == 31) SB[((size_t)b * 1025 + 1024) * 128 + co] = 0.f;
        for (int jj = 31; jj >= 0; --jj) {
            rB += pl[jj] * gs[jj * 128 + co];
            SB[((size_t)b * 1025 + seg * 32 + jj) * 128 + co] = rB;
        }
    }
}

// ---------------------------------------------------------------------------
// K6: out[b][co][n] = ((t[n]*SA[k(n)][co] + SB[k(n)][co])/M)*sc[co] + bs[co] + x
// ---------------------------------------------------------------------------
__global__ __launch_bounds__(256) void k_final(
    const float* __restrict__ x, const float* __restrict__ t,
    const float* __restrict__ ps, const float* __restrict__ SA, const float* __restrict__ SB,
    const float* __restrict__ b2, const float* __restrict__ gamma, const float* __restrict__ beta,
    const float* __restrict__ mean, const float* __restrict__ var,
    float* __restrict__ out)
{
    const int nt = blockIdx.x;     // 0..31 (128-pixel n tiles)
    const int b = blockIdx.y;
    const int tid = threadIdx.x;
    const int n0 = nt * 128;
    __shared__ float psl[1024];
    __shared__ float tl[128];
    __shared__ int   kl[128];
    __shared__ float sc[128], bs[128];
    __shared__ float sa_s[32][129], sb_s[32][129];

    for (int it = 0; it < 4; ++it) psl[tid + 256 * it] = ps[b * 1024 + tid + 256 * it];
    __syncthreads();
    if (tid < 128) {
        float tv = t[(size_t)b * Nn + n0 + tid];
        tl[tid] = tv;
        float key = -tv;
        int lo = 0, hi = 1024;
        while (lo < hi) { int mid = (lo + hi) >> 1; if (psl[mid] > key) hi = mid; else lo = mid + 1; }
        kl[tid] = lo;
    } else {
        int co = tid - 128;
        float s = gamma[co] * rsqrtf(var[co] + 1e-5f);
        sc[co] = s;
        bs[co] = (b2[co] - mean[co]) * s + beta[co];
    }
    __syncthreads();

    const float invM = 1.0f / 1024.0f;
    for (int sub = 0; sub < 4; ++sub) {
        for (int it = 0; it < 16; ++it) {
            int f = tid + 256 * it;          // 4096: 32 rows x 128 co
            int rowl = f >> 7, co = f & 127;
            int k = kl[sub * 32 + rowl];
            sa_s[rowl][co] = SA[((size_t)b * 1025 + k) * 128 + co];
            sb_s[rowl][co] = SB[((size_t)b * 1025 + k) * 128 + co];
        }
        __syncthreads();
        for (int it = 0; it < 4; ++it) {
            int f = tid + 256 * it;          // 1024 float4s: 128 co x 8 n-quads
            int co = f >> 3, nn0 = (f & 7) * 4;
            size_t gidx = ((size_t)b * Cn + co) * Nn + n0 + sub * 32 + nn0;
            float4 xv = *(const float4*)&x[gidx];
            float scv = sc[co], bsv = bs[co];
            float4 o;
            float v0 = (tl[sub*32+nn0+0] * sa_s[nn0+0][co] + sb_s[nn0+0][co]) * invM;
            float v1 = (tl[sub*32+nn0+1] * sa_s[nn0+1][co] + sb_s[nn0+1][co]) * invM;
            float v2 = (tl[sub*32+nn0+2] * sa_s[nn0+2][co] + sb_s[nn0+2][co]) * invM;
            float v3 = (tl[sub*32+nn0+3] * sa_s[nn0+3][co] + sb_s[nn0+3][co]) * invM;
            o.x = v0 * scv + bsv + xv.x;
            o.y = v1 * scv + bsv + xv.y;
            o.z = v2 * scv + bsv + xv.z;
            o.w = v3 * scv + bsv + xv.w;
            *(float4*)&out[gidx] = o;
        }
        __syncthreads();
    }
}

// ---------------------------------------------------------------------------
extern "C" void kernel_launch(void* const* d_in, const int* in_sizes, int n_in,
                              void* d_out, int out_size, void* d_ws, size_t ws_size,
                              hipStream_t stream)
{
    const float* x  = (const float*)d_in[0];
    const float* w1 = (const float*)d_in[1];
    const float* b1 = (const float*)d_in[2];
    const float* w3 = (const float*)d_in[3];
    const float* b3 = (const float*)d_in[4];
    const float* w4 = (const float*)d_in[5];
    const float* b4 = (const float*)d_in[6];
    const float* w5 = (const float*)d_in[7];
    const float* w2 = (const float*)d_in[8];
    const float* b2 = (const float*)d_in[9];
    const float* gm = (const float*)d_in[10];
    const float* bt = (const float*)d_in[11];
    const float* mn = (const float*)d_in[12];
    const float* vr = (const float*)d_in[13];
    float* out = (float*)d_out;

    float* ws = (float*)d_ws;
    const size_t FTOT = 3811584;           // floats (~15.25 MB)
    if (ws_size < FTOT * sizeof(float)) return;

    float* t_w  = ws;                      // 32768
    float* p_w  = ws + 32768;              // 8192
    float* ps_w = ws + 40960;              // 8192
    int*   pm_w = (int*)(ws + 49152);      // 8192
    float* g_w  = ws + 581632;             // 1048576
    float* csa  = ws + 1630208;            // 32768
    float* csb  = ws + 1662976;            // 32768
    float* SAp  = ws + 1695744;            // 1049600
    float* SBp  = ws + 2745344;            // 1049600
    float* wpk  = ws + 3794944;            // 16384
    float* ucon = ws + 3811328;            // 256

    k_pre  <<<9,           256, 0, stream>>>(w1, w4, w3, b3, w5, wpk, ucon);
    k_conv <<<dim3(64, 8), 256, 0, stream>>>(x, b1, b4, wpk, ucon, w2, t_w, p_w, g_w);
    k_rank <<<dim3(8, 8),  128, 0, stream>>>(p_w, ps_w, pm_w);
    k_scanA<<<dim3(32, 8), 256, 0, stream>>>(g_w, ps_w, pm_w, csa, csb);
    k_scanC<<<dim3(32, 8), 256, 0, stream>>>(g_w, ps_w, pm_w, csa, csb, SAp, SBp);
    k_final<<<dim3(32, 8), 256, 0, stream>>>(x, t_w, ps_w, SAp, SBp, b2, gm, bt, mn, vr, out);
}

// Round 5
// 152.260 us; speedup vs baseline: 1.1450x; 1.0556x over previous
//
#include <hip/hip_runtime.h>

typedef unsigned int u32;
typedef unsigned short u16;

#define Cn 128
#define ICn 64
#define Nn 4096
#define Mn 1024

typedef __attribute__((ext_vector_type(8))) short s8v;   // 8 bf16 (4 VGPRs)
typedef __attribute__((ext_vector_type(4))) float f4v;   // 4 fp32 acc

__device__ __forceinline__ float bf2f(u16 u){ union{u32 i; float f;} v; v.i = ((u32)u) << 16; return v.f; }
__device__ __forceinline__ u16 f2bf(float f){ union{float f; u32 i;} v; v.f = f; u32 r = v.i + 0x7fffu + ((v.i >> 16) & 1u); return (u16)(r >> 16); }

// ---------------------------------------------------------------------------
// K0: ucon[0..127]=u3 (W3^T wt), ucon[128]=c3 (wt.b3), ucon[129..192]=wp
// ---------------------------------------------------------------------------
__global__ __launch_bounds__(256) void k_pre(
    const float* __restrict__ w3, const float* __restrict__ b3,
    const float* __restrict__ w5, float* __restrict__ ucon)
{
    const int tid = threadIdx.x;
    if (tid < 128) {
        float s = 0.f;
        for (int ic = 0; ic < 64; ++ic) s += w5[ic] * w3[ic * Cn + tid];
        ucon[tid] = s;
    } else if (tid == 128) {
        float s = 0.f;
        for (int ic = 0; ic < 64; ++ic) s += w5[ic] * b3[ic];
        ucon[128] = s;
    } else if (tid < 193) {
        ucon[129 + (tid - 129)] = w5[64 + (tid - 129)];
    }
}

// ---------------------------------------------------------------------------
// K1 (MFMA): per (row-pair r, half-width wb, batch b):
//   bf16 stage x^T, W1, W4 -> MFMA dual conv (64ic x 128c x 64px)
//   -> pool(a1) -> xgr -> MFMA g = xgr.W2^T ; pool(a4) -> p ; t = u3.x+c3.
// LDS u16 smem[32768] = 64 KB:
//   xsT  @0      [64 lp][136 c]   (8704)
//   w1t  @8704   [64 ic][136 c]   (8704)
//   w4t  @17408  [64 ic][136 c]   (8704)
//   ph   @26112  f32 [32][68]     (4352 u16-units = 2176 f32)
//   phase B (w1t/w4t dead): w2t @8704 [128 co][72 ic] (9216); xgr @17920 [16 pw][72 ic] (1152)
// ---------------------------------------------------------------------------
__global__ __launch_bounds__(256) void k_conv(
    const float* __restrict__ x, const float* __restrict__ b1, const float* __restrict__ b4,
    const float* __restrict__ w1, const float* __restrict__ w4,
    const float* __restrict__ ucon, const float* __restrict__ w2,
    float* __restrict__ t_o, float* __restrict__ p_o, float* __restrict__ g_o)
{
    const int tile = blockIdx.x;   // 0..63
    const int r  = tile >> 1;      // row-pair 0..31
    const int wb = tile & 1;       // half-width 0..1
    const int b  = blockIdx.y;
    const int tid = threadIdx.x;

    __shared__ u16 smem[32768];
    u16* xsT = smem;               // [64][136]
    u16* w1t = smem + 8704;        // [64][136]
    u16* w4t = smem + 17408;       // [64][136]
    float* ph = (float*)&smem[26112]; // [32][68] f32
    u16* w2t = smem + 8704;        // phase B [128][72]
    u16* xgr = smem + 17920;       // phase B [16][72]

    // ---- stage x^T as bf16 (coalesced f32 reads, scattered u16 writes) ----
    #pragma unroll
    for (int it = 0; it < 8; ++it) {
        int f = tid + 256 * it;        // 2048 float4s
        int c = f >> 4, rem = f & 15;
        int rl = rem >> 3, wq = rem & 7;
        const float* src = x + ((size_t)(b * Cn + c)) * Nn + (2 * r + rl) * 64 + 32 * wb + 4 * wq;
        float4 v = *(const float4*)src;
        int lp0 = rl * 32 + 4 * wq;
        xsT[(lp0 + 0) * 136 + c] = f2bf(v.x);
        xsT[(lp0 + 1) * 136 + c] = f2bf(v.y);
        xsT[(lp0 + 2) * 136 + c] = f2bf(v.z);
        xsT[(lp0 + 3) * 136 + c] = f2bf(v.w);
    }
    // ---- stage W1, W4 as bf16 rows (fully coalesced) ----
    #pragma unroll
    for (int it = 0; it < 8; ++it) {
        int f = tid + 256 * it;        // 2048 quads: ic = f>>5, cq = f&31
        int ic = f >> 5, cq = f & 31;
        float4 a = *(const float4*)&w1[ic * Cn + 4 * cq];
        float4 d = *(const float4*)&w4[ic * Cn + 4 * cq];
        ushort4 pa = { f2bf(a.x), f2bf(a.y), f2bf(a.z), f2bf(a.w) };
        ushort4 pd = { f2bf(d.x), f2bf(d.y), f2bf(d.z), f2bf(d.w) };
        *(ushort4*)&w1t[ic * 136 + 4 * cq] = pa;
        *(ushort4*)&w4t[ic * 136 + 4 * cq] = pd;
    }
    __syncthreads();

    const int lane = tid & 63;
    const int wv   = tid >> 6;         // wave 0..3 -> lp block [16wv,16wv+16)
    const int col  = lane & 15;
    const int quad = lane >> 4;

    // ---- dual conv MFMA: D[ic][lp] ----
    f4v acc1[4] = {}, acc4[4] = {};
    const u16* xrow = &xsT[(16 * wv + col) * 136];
    #pragma unroll
    for (int kb = 0; kb < 4; ++kb) {
        s8v bx = *(const s8v*)&xrow[kb * 32 + quad * 8];
        #pragma unroll
        for (int icb = 0; icb < 4; ++icb) {
            s8v a1 = *(const s8v*)&w1t[(icb * 16 + col) * 136 + kb * 32 + quad * 8];
            s8v a4 = *(const s8v*)&w4t[(icb * 16 + col) * 136 + kb * 32 + quad * 8];
            acc1[icb] = __builtin_amdgcn_mfma_f32_16x16x32_bf16(a1, bx, acc1[icb], 0, 0, 0);
            acc4[icb] = __builtin_amdgcn_mfma_f32_16x16x32_bf16(a4, bx, acc4[icb], 0, 0, 0);
        }
    }
    __syncthreads();   // MFMA LDS reads done; w1t/w4t dead

    // ---- a1: horizontal pair max in-register, write half-pool to ph ----
    const int lp = 16 * wv + col;
    const int rl = lp >> 5, wl = lp & 31, pw = wl >> 1;
    const bool wr = (wl & 1) == 0;
    #pragma unroll
    for (int icb = 0; icb < 4; ++icb)
        #pragma unroll
        for (int reg = 0; reg < 4; ++reg) {
            float v = acc1[icb][reg];
            float vm = fmaxf(v, __shfl_xor(v, 1, 64));
            if (wr) ph[(rl * 16 + pw) * 68 + icb * 16 + quad * 4 + reg] = vm;
        }
    __syncthreads();

    // ---- xgr = vertical pool + bias (bf16); t from xsT ----
    #pragma unroll
    for (int it = 0; it < 4; ++it) {
        int e = tid + 256 * it;        // 1024: pw = e>>6, ic = e&63
        int pwq = e >> 6, ic = e & 63;
        float v = fmaxf(ph[pwq * 68 + ic], ph[(16 + pwq) * 68 + ic]) + b1[ic];
        xgr[pwq * 72 + ic] = f2bf(v);
    }
    if (tid < 64) {
        float s = ucon[128];
        const u16* xr = &xsT[tid * 136];
        for (int cq = 0; cq < 16; ++cq) {
            s8v xv = *(const s8v*)&xr[cq * 8];
            #pragma unroll
            for (int j = 0; j < 8; ++j)
                s += ucon[cq * 8 + j] * bf2f((u16)xv[j]);
        }
        t_o[(size_t)b * Nn + (2 * r + (tid >> 5)) * 64 + 32 * wb + (tid & 31)] = s;
    }
    __syncthreads();   // xgr ready; ph consumed

    // ---- stage W2 bf16 rows [co][ic]; a4 half-pool -> ph ----
    #pragma unroll
    for (int it = 0; it < 8; ++it) {
        int f = tid + 256 * it;        // 2048 quads: co = f>>4, iq = f&15
        int co = f >> 4, iq = f & 15;
        float4 v = *(const float4*)&w2[co * 64 + 4 * iq];
        ushort4 pv = { f2bf(v.x), f2bf(v.y), f2bf(v.z), f2bf(v.w) };
        *(ushort4*)&w2t[co * 72 + 4 * iq] = pv;
    }
    #pragma unroll
    for (int icb = 0; icb < 4; ++icb)
        #pragma unroll
        for (int reg = 0; reg < 4; ++reg) {
            float v = acc4[icb][reg];
            float vm = fmaxf(v, __shfl_xor(v, 1, 64));
            if (wr) ph[(rl * 16 + pw) * 68 + icb * 16 + quad * 4 + reg] = vm;
        }
    __syncthreads();

    // ---- g = xgr . W2^T via MFMA: wave wv -> co blocks {2wv, 2wv+1} ----
    #pragma unroll
    for (int cob2 = 0; cob2 < 2; ++cob2) {
        int cob = 2 * wv + cob2;
        f4v gacc = {};
        #pragma unroll
        for (int kb = 0; kb < 2; ++kb) {
            s8v a  = *(const s8v*)&xgr[col * 72 + kb * 32 + quad * 8];
            s8v bb = *(const s8v*)&w2t[(cob * 16 + col) * 72 + kb * 32 + quad * 8];
            gacc = __builtin_amdgcn_mfma_f32_16x16x32_bf16(a, bb, gacc, 0, 0, 0);
        }
        #pragma unroll
        for (int reg = 0; reg < 4; ++reg) {
            int pwr = quad * 4 + reg;
            int m = r * 32 + wb * 16 + pwr;
            g_o[((size_t)b * Mn + m) * 128 + cob * 16 + col] = gacc[reg];
        }
    }

    // ---- p from a4 pool ----
    if (tid < 16) {
        float s = 0.f;
        for (int ic = 0; ic < 64; ++ic) {
            float pv = fmaxf(ph[tid * 68 + ic], ph[(16 + tid) * 68 + ic]) + b4[ic];
            s += ucon[129 + ic] * pv;
        }
        p_o[(size_t)b * Mn + r * 32 + wb * 16 + tid] = s;
    }
}

// ---------------------------------------------------------------------------
// K3: rank-by-counting sort (barrier-free after load).
// ---------------------------------------------------------------------------
__global__ __launch_bounds__(128) void k_rank(
    const float* __restrict__ p, float* __restrict__ ps, int* __restrict__ perm)
{
    const int mc = blockIdx.x;     // 0..7
    const int b  = blockIdx.y;
    const int tid = threadIdx.x;
    __shared__ float pls[1024];
    #pragma unroll
    for (int it = 0; it < 2; ++it) {
        int f = tid + 128 * it;
        *(float4*)&pls[f * 4] = *(const float4*)&p[b * 1024 + f * 4];
    }
    __syncthreads();
    const int m = mc * 128 + tid;
    const float key = pls[m];
    int rank = 0;
    #pragma unroll 8
    for (int j = 0; j < 1024; ++j) {
        float v = pls[j];
        rank += (v < key || (v == key && j < m)) ? 1 : 0;
    }
    ps[b * 1024 + rank]   = key;
    perm[b * 1024 + rank] = m;
}

// ---------------------------------------------------------------------------
// K4: per 32-j segment chunk sums of g_sorted and p*g_sorted
// ---------------------------------------------------------------------------
__global__ __launch_bounds__(256) void k_scanA(
    const float* __restrict__ g, const float* __restrict__ ps, const int* __restrict__ perm,
    float* __restrict__ csa, float* __restrict__ csb)
{
    const int seg = blockIdx.x;
    const int b = blockIdx.y;
    const int tid = threadIdx.x;
    const int co = tid & 127, jh = tid >> 7;
    __shared__ float redA[2][128], redB[2][128];
    __shared__ float pl[32];
    __shared__ int   pml[32];
    if (tid < 32) { pl[tid] = ps[b * 1024 + seg * 32 + tid]; pml[tid] = perm[b * 1024 + seg * 32 + tid]; }
    __syncthreads();
    float sA = 0.f, sB = 0.f;
    for (int jj = jh * 16; jj < jh * 16 + 16; ++jj) {
        float gv = g[((size_t)b * Mn + pml[jj]) * 128 + co];
        sA += gv; sB += pl[jj] * gv;
    }
    redA[jh][co] = sA; redB[jh][co] = sB;
    __syncthreads();
    if (tid < 128) {
        csa[(b * 32 + seg) * 128 + tid] = redA[0][tid] + redA[1][tid];
        csb[(b * 32 + seg) * 128 + tid] = redB[0][tid] + redB[1][tid];
    }
}

// ---------------------------------------------------------------------------
// K5: suffix-sum walk -> SA[b][k][co], SB[b][k][co], k in [0,1024].
// ---------------------------------------------------------------------------
__global__ __launch_bounds__(256) void k_scanC(
    const float* __restrict__ g, const float* __restrict__ ps, const int* __restrict__ perm,
    const float* __restrict__ csa, const float* __restrict__ csb,
    float* __restrict__ SA, float* __restrict__ SB)
{
    const int seg = blockIdx.x;
    const int b = blockIdx.y;
    const int tid = threadIdx.x;
    __shared__ float gs[32 * 128];
    __shared__ float pl[32];
    __shared__ int   pml[32];
    if (tid < 32) { pl[tid] = ps[b * 1024 + seg * 32 + tid]; pml[tid] = perm[b * 1024 + seg * 32 + tid]; }
    __syncthreads();
    for (int it = 0; it < 16; ++it) {
        int f = tid + 256 * it;
        int jj = f >> 7, co = f & 127;
        gs[jj * 128 + co] = g[((size_t)b * Mn + pml[jj]) * 128 + co];
    }
    __syncthreads();

    const int co = tid & 127;
    if (tid < 128) {
        float rA = 0.f;
        for (int s = seg + 1; s < 32; ++s) rA += csa[(b * 32 + s) * 128 + co];
        if (seg == 31) SA[((size_t)b * 1025 + 1024) * 128 + co] = 0.f;
        for (int jj = 31; jj >= 0; --jj) {
            rA += gs[jj * 128 + co];
            SA[((size_t)b * 1025 + seg * 32 + jj) * 128 + co] = rA;
        }
    } else {
        float rB = 0.f;
        for (int s = seg + 1; s < 32; ++s) rB += csb[(b * 32 + s) * 128 + co];
        if (seg == 31) SB[((size_t)b * 1025 + 1024) * 128 + co] = 0.f;
        for (int jj = 31; jj >= 0; --jj) {
            rB += pl[jj] * gs[jj * 128 + co];
            SB[((size_t)b * 1025 + seg * 32 + jj) * 128 + co] = rB;
        }
    }
}

// ---------------------------------------------------------------------------
// K6: out[b][co][n] = ((t[n]*SA[k(n)][co] + SB[k(n)][co])/M)*sc[co] + bs[co] + x
// ---------------------------------------------------------------------------
__global__ __launch_bounds__(256) void k_final(
    const float* __restrict__ x, const float* __restrict__ t,
    const float* __restrict__ ps, const float* __restrict__ SA, const float* __restrict__ SB,
    const float* __restrict__ b2, const float* __restrict__ gamma, const float* __restrict__ beta,
    const float* __restrict__ mean, const float* __restrict__ var,
    float* __restrict__ out)
{
    const int nt = blockIdx.x;
    const int b = blockIdx.y;
    const int tid = threadIdx.x;
    const int n0 = nt * 128;
    __shared__ float psl[1024];
    __shared__ float tl[128];
    __shared__ int   kl[128];
    __shared__ float sc[128], bs[128];
    __shared__ float sa_s[32][129], sb_s[32][129];

    for (int it = 0; it < 4; ++it) psl[tid + 256 * it] = ps[b * 1024 + tid + 256 * it];
    __syncthreads();
    if (tid < 128) {
        float tv = t[(size_t)b * Nn + n0 + tid];
        tl[tid] = tv;
        float key = -tv;
        int lo = 0, hi = 1024;
        while (lo < hi) { int mid = (lo + hi) >> 1; if (psl[mid] > key) hi = mid; else lo = mid + 1; }
        kl[tid] = lo;
    } else {
        int co = tid - 128;
        float s = gamma[co] * rsqrtf(var[co] + 1e-5f);
        sc[co] = s;
        bs[co] = (b2[co] - mean[co]) * s + beta[co];
    }
    __syncthreads();

    const float invM = 1.0f / 1024.0f;
    for (int sub = 0; sub < 4; ++sub) {
        for (int it = 0; it < 16; ++it) {
            int f = tid + 256 * it;
            int rowl = f >> 7, co = f & 127;
            int k = kl[sub * 32 + rowl];
            sa_s[rowl][co] = SA[((size_t)b * 1025 + k) * 128 + co];
            sb_s[rowl][co] = SB[((size_t)b * 1025 + k) * 128 + co];
        }
        __syncthreads();
        for (int it = 0; it < 4; ++it) {
            int f = tid + 256 * it;
            int co = f >> 3, nn0 = (f & 7) * 4;
            size_t gidx = ((size_t)b * Cn + co) * Nn + n0 + sub * 32 + nn0;
            float4 xv = *(const float4*)&x[gidx];
            float scv = sc[co], bsv = bs[co];
            float4 o;
            float v0 = (tl[sub*32+nn0+0] * sa_s[nn0+0][co] + sb_s[nn0+0][co]) * invM;
            float v1 = (tl[sub*32+nn0+1] * sa_s[nn0+1][co] + sb_s[nn0+1][co]) * invM;
            float v2 = (tl[sub*32+nn0+2] * sa_s[nn0+2][co] + sb_s[nn0+2][co]) * invM;
            float v3 = (tl[sub*32+nn0+3] * sa_s[nn0+3][co] + sb_s[nn0+3][co]) * invM;
            o.x = v0 * scv + bsv + xv.x;
            o.y = v1 * scv + bsv + xv.y;
            o.z = v2 * scv + bsv + xv.z;
            o.w = v3 * scv + bsv + xv.w;
            *(float4*)&out[gidx] = o;
        }
        __syncthreads();
    }
}

// ---------------------------------------------------------------------------
extern "C" void kernel_launch(void* const* d_in, const int* in_sizes, int n_in,
                              void* d_out, int out_size, void* d_ws, size_t ws_size,
                              hipStream_t stream)
{
    const float* x  = (const float*)d_in[0];
    const float* w1 = (const float*)d_in[1];
    const float* b1 = (const float*)d_in[2];
    const float* w3 = (const float*)d_in[3];
    const float* b3 = (const float*)d_in[4];
    const float* w4 = (const float*)d_in[5];
    const float* b4 = (const float*)d_in[6];
    const float* w5 = (const float*)d_in[7];
    const float* w2 = (const float*)d_in[8];
    const float* b2 = (const float*)d_in[9];
    const float* gm = (const float*)d_in[10];
    const float* bt = (const float*)d_in[11];
    const float* mn = (const float*)d_in[12];
    const float* vr = (const float*)d_in[13];
    float* out = (float*)d_out;

    float* ws = (float*)d_ws;
    const size_t FTOT = 3811584;           // floats (~15.25 MB)
    if (ws_size < FTOT * sizeof(float)) return;

    float* t_w  = ws;                      // 32768
    float* p_w  = ws + 32768;              // 8192
    float* ps_w = ws + 40960;              // 8192
    int*   pm_w = (int*)(ws + 49152);      // 8192
    float* g_w  = ws + 581632;             // 1048576
    float* csa  = ws + 1630208;            // 32768
    float* csb  = ws + 1662976;            // 32768
    float* SAp  = ws + 1695744;            // 1049600
    float* SBp  = ws + 2745344;            // 1049600
    float* ucon = ws + 3811328;            // 256

    k_pre  <<<1,           256, 0, stream>>>(w3, b3, w5, ucon);
    k_conv <<<dim3(64, 8), 256, 0, stream>>>(x, b1, b4, w1, w4, ucon, w2, t_w, p_w, g_w);
    k_rank <<<dim3(8, 8),  128, 0, stream>>>(p_w, ps_w, pm_w);
    k_scanA<<<dim3(32, 8), 256, 0, stream>>>(g_w, ps_w, pm_w, csa, csb);
    k_scanC<<<dim3(32, 8), 256, 0, stream>>>(g_w, ps_w, pm_w, csa, csb, SAp, SBp);
    k_final<<<dim3(32, 8), 256, 0, stream>>>(x, t_w, ps_w, SAp, SBp, b2, gm, bt, mn, vr, out);
}

// Round 6
// 150.388 us; speedup vs baseline: 1.1592x; 1.0125x over previous
//
#include <hip/hip_runtime.h>

typedef unsigned int u32;
typedef unsigned short u16;

#define Cn 128
#define ICn 64
#define Nn 4096
#define Mn 1024

typedef __attribute__((ext_vector_type(8))) short s8v;   // 8 bf16 (4 VGPRs)
typedef __attribute__((ext_vector_type(4))) float f4v;   // 4 fp32 acc

__device__ __forceinline__ float bf2f(u16 u){ union{u32 i; float f;} v; v.i = ((u32)u) << 16; return v.f; }
__device__ __forceinline__ u16 f2bf(float f){ union{float f; u32 i;} v; v.f = f; u32 r = v.i + 0x7fffu + ((v.i >> 16) & 1u); return (u16)(r >> 16); }

// ---------------------------------------------------------------------------
// K0: blocks 0..7: convert w1,w4,w2 -> bf16 flat (1024 elems each per block).
//     block 8: ucon[0..127]=u3 (W3^T wt), ucon[128]=c3, ucon[129..192]=wp
// ---------------------------------------------------------------------------
__global__ __launch_bounds__(256) void k_pre(
    const float* __restrict__ w1, const float* __restrict__ w4,
    const float* __restrict__ w2,
    const float* __restrict__ w3, const float* __restrict__ b3,
    const float* __restrict__ w5,
    u16* __restrict__ w1b, u16* __restrict__ w4b, u16* __restrict__ w2b,
    float* __restrict__ ucon)
{
    const int blk = blockIdx.x;
    const int tid = threadIdx.x;
    if (blk < 8) {
        #pragma unroll
        for (int it = 0; it < 4; ++it) {
            int e = blk * 1024 + it * 256 + tid;   // 0..8191
            w1b[e] = f2bf(w1[e]);
            w4b[e] = f2bf(w4[e]);
            w2b[e] = f2bf(w2[e]);
        }
    } else {
        if (tid < 128) {
            float s = 0.f;
            for (int ic = 0; ic < 64; ++ic) s += w5[ic] * w3[ic * Cn + tid];
            ucon[tid] = s;
        } else if (tid == 128) {
            float s = 0.f;
            for (int ic = 0; ic < 64; ++ic) s += w5[ic] * b3[ic];
            ucon[128] = s;
        } else if (tid < 193) {
            ucon[129 + (tid - 129)] = w5[64 + (tid - 129)];
        }
    }
}

// ---------------------------------------------------------------------------
// K1 (MFMA): per (row-pair r, half-width wb, batch b):
//   bf16 stage x^T, W1, W4 -> MFMA dual conv (64ic x 128c x 64px)
//   -> pool(a1) -> xgr -> MFMA g = xgr.W2^T ; pool(a4) -> p ; t = u3.x+c3.
// LDS u16 smem[32768] = 64 KB:
//   xsT  @0      [64 lp][136 c]   (8704)
//   w1t  @8704   [64 ic][136 c]   (8704)
//   w4t  @17408  [64 ic][136 c]   (8704)
//   ph   @26112  f32 [32][68]     (4352 u16-units = 2176 f32)
//   phase B (w1t/w4t dead): w2t @8704 [128 co][72 ic] (9216); xgr @17920 [16 pw][72 ic]
// ---------------------------------------------------------------------------
__global__ __launch_bounds__(256) void k_conv(
    const float* __restrict__ x, const float* __restrict__ b1, const float* __restrict__ b4,
    const u16* __restrict__ w1b, const u16* __restrict__ w4b,
    const float* __restrict__ ucon, const u16* __restrict__ w2b,
    float* __restrict__ t_o, float* __restrict__ p_o, float* __restrict__ g_o)
{
    const int tile = blockIdx.x;   // 0..63
    const int r  = tile >> 1;      // row-pair 0..31
    const int wb = tile & 1;       // half-width 0..1
    const int b  = blockIdx.y;
    const int tid = threadIdx.x;

    __shared__ u16 smem[32768];
    u16* xsT = smem;               // [64][136]
    u16* w1t = smem + 8704;        // [64][136]
    u16* w4t = smem + 17408;       // [64][136]
    float* ph = (float*)&smem[26112]; // [32][68] f32
    u16* w2t = smem + 8704;        // phase B [128][72]
    u16* xgr = smem + 17920;       // phase B [16][72]

    // ---- stage x^T as bf16 (coalesced f32 reads, scattered u16 writes) ----
    #pragma unroll
    for (int it = 0; it < 8; ++it) {
        int f = tid + 256 * it;        // 2048 float4s
        int c = f >> 4, rem = f & 15;
        int rl = rem >> 3, wq = rem & 7;
        const float* src = x + ((size_t)(b * Cn + c)) * Nn + (2 * r + rl) * 64 + 32 * wb + 4 * wq;
        float4 v = *(const float4*)src;
        int lp0 = rl * 32 + 4 * wq;
        xsT[(lp0 + 0) * 136 + c] = f2bf(v.x);
        xsT[(lp0 + 1) * 136 + c] = f2bf(v.y);
        xsT[(lp0 + 2) * 136 + c] = f2bf(v.z);
        xsT[(lp0 + 3) * 136 + c] = f2bf(v.w);
    }
    // ---- stage W1, W4 bf16 (uint4 loads, ds_write_b128) ----
    #pragma unroll
    for (int it = 0; it < 4; ++it) {
        int f = tid + 256 * it;        // 1024 ushort8s: ic = f>>4, cq = f&15
        int ic = f >> 4, cq = f & 15;
        uint4 a = *(const uint4*)&w1b[f * 8];
        uint4 d = *(const uint4*)&w4b[f * 8];
        *(uint4*)&w1t[ic * 136 + 8 * cq] = a;
        *(uint4*)&w4t[ic * 136 + 8 * cq] = d;
    }
    __syncthreads();

    const int lane = tid & 63;
    const int wv   = tid >> 6;         // wave 0..3 -> lp block [16wv,16wv+16)
    const int col  = lane & 15;
    const int quad = lane >> 4;

    // ---- dual conv MFMA: D[ic][lp] ----
    f4v acc1[4] = {}, acc4[4] = {};
    const u16* xrow = &xsT[(16 * wv + col) * 136];
    #pragma unroll
    for (int kb = 0; kb < 4; ++kb) {
        s8v bx = *(const s8v*)&xrow[kb * 32 + quad * 8];
        #pragma unroll
        for (int icb = 0; icb < 4; ++icb) {
            s8v a1 = *(const s8v*)&w1t[(icb * 16 + col) * 136 + kb * 32 + quad * 8];
            s8v a4 = *(const s8v*)&w4t[(icb * 16 + col) * 136 + kb * 32 + quad * 8];
            acc1[icb] = __builtin_amdgcn_mfma_f32_16x16x32_bf16(a1, bx, acc1[icb], 0, 0, 0);
            acc4[icb] = __builtin_amdgcn_mfma_f32_16x16x32_bf16(a4, bx, acc4[icb], 0, 0, 0);
        }
    }
    __syncthreads();   // MFMA LDS reads done; w1t/w4t dead

    // ---- a1: horizontal pair max in-register, write half-pool to ph ----
    const int lp = 16 * wv + col;
    const int rl = lp >> 5, wl = lp & 31, pw = wl >> 1;
    const bool wr = (wl & 1) == 0;
    #pragma unroll
    for (int icb = 0; icb < 4; ++icb)
        #pragma unroll
        for (int reg = 0; reg < 4; ++reg) {
            float v = acc1[icb][reg];
            float vm = fmaxf(v, __shfl_xor(v, 1, 64));
            if (wr) ph[(rl * 16 + pw) * 68 + icb * 16 + quad * 4 + reg] = vm;
        }
    __syncthreads();

    // ---- xgr = vertical pool + bias (bf16); t from xsT ----
    #pragma unroll
    for (int it = 0; it < 4; ++it) {
        int e = tid + 256 * it;        // 1024: pw = e>>6, ic = e&63
        int pwq = e >> 6, ic = e & 63;
        float v = fmaxf(ph[pwq * 68 + ic], ph[(16 + pwq) * 68 + ic]) + b1[ic];
        xgr[pwq * 72 + ic] = f2bf(v);
    }
    if (tid < 64) {
        float s = ucon[128];
        const u16* xr = &xsT[tid * 136];
        for (int cq = 0; cq < 16; ++cq) {
            s8v xv = *(const s8v*)&xr[cq * 8];
            #pragma unroll
            for (int j = 0; j < 8; ++j)
                s += ucon[cq * 8 + j] * bf2f((u16)xv[j]);
        }
        t_o[(size_t)b * Nn + (2 * r + (tid >> 5)) * 64 + 32 * wb + (tid & 31)] = s;
    }
    __syncthreads();   // xgr ready; ph consumed

    // ---- stage W2 bf16 [co][72]; a4 half-pool -> ph ----
    #pragma unroll
    for (int it = 0; it < 4; ++it) {
        int f = tid + 256 * it;        // 1024 ushort8s: co = f>>3, iq = f&7
        int co = f >> 3, iq = f & 7;
        uint4 v = *(const uint4*)&w2b[f * 8];
        *(uint4*)&w2t[co * 72 + 8 * iq] = v;
    }
    #pragma unroll
    for (int icb = 0; icb < 4; ++icb)
        #pragma unroll
        for (int reg = 0; reg < 4; ++reg) {
            float v = acc4[icb][reg];
            float vm = fmaxf(v, __shfl_xor(v, 1, 64));
            if (wr) ph[(rl * 16 + pw) * 68 + icb * 16 + quad * 4 + reg] = vm;
        }
    __syncthreads();

    // ---- g = xgr . W2^T via MFMA: wave wv -> co blocks {2wv, 2wv+1} ----
    #pragma unroll
    for (int cob2 = 0; cob2 < 2; ++cob2) {
        int cob = 2 * wv + cob2;
        f4v gacc = {};
        #pragma unroll
        for (int kb = 0; kb < 2; ++kb) {
            s8v a  = *(const s8v*)&xgr[col * 72 + kb * 32 + quad * 8];
            s8v bb = *(const s8v*)&w2t[(cob * 16 + col) * 72 + kb * 32 + quad * 8];
            gacc = __builtin_amdgcn_mfma_f32_16x16x32_bf16(a, bb, gacc, 0, 0, 0);
        }
        #pragma unroll
        for (int reg = 0; reg < 4; ++reg) {
            int pwr = quad * 4 + reg;
            int m = r * 32 + wb * 16 + pwr;
            g_o[((size_t)b * Mn + m) * 128 + cob * 16 + col] = gacc[reg];
        }
    }

    // ---- p from a4 pool ----
    if (tid < 16) {
        float s = 0.f;
        for (int ic = 0; ic < 64; ++ic) {
            float pv = fmaxf(ph[tid * 68 + ic], ph[(16 + tid) * 68 + ic]) + b4[ic];
            s += ucon[129 + ic] * pv;
        }
        p_o[(size_t)b * Mn + r * 32 + wb * 16 + tid] = s;
    }
}

// ---------------------------------------------------------------------------
// K3: rank-by-counting sort (barrier-free after load).
// ---------------------------------------------------------------------------
__global__ __launch_bounds__(128) void k_rank(
    const float* __restrict__ p, float* __restrict__ ps, int* __restrict__ perm)
{
    const int mc = blockIdx.x;     // 0..7
    const int b  = blockIdx.y;
    const int tid = threadIdx.x;
    __shared__ float pls[1024];
    #pragma unroll
    for (int it = 0; it < 2; ++it) {
        int f = tid + 128 * it;
        *(float4*)&pls[f * 4] = *(const float4*)&p[b * 1024 + f * 4];
    }
    __syncthreads();
    const int m = mc * 128 + tid;
    const float key = pls[m];
    int rank = 0;
    #pragma unroll 8
    for (int j = 0; j < 1024; ++j) {
        float v = pls[j];
        rank += (v < key || (v == key && j < m)) ? 1 : 0;
    }
    ps[b * 1024 + rank]   = key;
    perm[b * 1024 + rank] = m;
}

// ---------------------------------------------------------------------------
// K4: per 32-j segment chunk sums of g_sorted and p*g_sorted
// ---------------------------------------------------------------------------
__global__ __launch_bounds__(256) void k_scanA(
    const float* __restrict__ g, const float* __restrict__ ps, const int* __restrict__ perm,
    float* __restrict__ csa, float* __restrict__ csb)
{
    const int seg = blockIdx.x;
    const int b = blockIdx.y;
    const int tid = threadIdx.x;
    const int co = tid & 127, jh = tid >> 7;
    __shared__ float redA[2][128], redB[2][128];
    __shared__ float pl[32];
    __shared__ int   pml[32];
    if (tid < 32) { pl[tid] = ps[b * 1024 + seg * 32 + tid]; pml[tid] = perm[b * 1024 + seg * 32 + tid]; }
    __syncthreads();
    float sA = 0.f, sB = 0.f;
    for (int jj = jh * 16; jj < jh * 16 + 16; ++jj) {
        float gv = g[((size_t)b * Mn + pml[jj]) * 128 + co];
        sA += gv; sB += pl[jj] * gv;
    }
    redA[jh][co] = sA; redB[jh][co] = sB;
    __syncthreads();
    if (tid < 128) {
        csa[(b * 32 + seg) * 128 + tid] = redA[0][tid] + redA[1][tid];
        csb[(b * 32 + seg) * 128 + tid] = redB[0][tid] + redB[1][tid];
    }
}

// ---------------------------------------------------------------------------
// K5: suffix-sum walk -> SA[b][k][co], SB[b][k][co], k in [0,1024].
// ---------------------------------------------------------------------------
__global__ __launch_bounds__(256) void k_scanC(
    const float* __restrict__ g, const float* __restrict__ ps, const int* __restrict__ perm,
    const float* __restrict__ csa, const float* __restrict__ csb,
    float* __restrict__ SA, float* __restrict__ SB)
{
    const int seg = blockIdx.x;
    const int b = blockIdx.y;
    const int tid = threadIdx.x;
    __shared__ float gs[32 * 128];
    __shared__ float pl[32];
    __shared__ int   pml[32];
    if (tid < 32) { pl[tid] = ps[b * 1024 + seg * 32 + tid]; pml[tid] = perm[b * 1024 + seg * 32 + tid]; }
    __syncthreads();
    for (int it = 0; it < 16; ++it) {
        int f = tid + 256 * it;
        int jj = f >> 7, co = f & 127;
        gs[jj * 128 + co] = g[((size_t)b * Mn + pml[jj]) * 128 + co];
    }
    __syncthreads();

    const int co = tid & 127;
    if (tid < 128) {
        float rA = 0.f;
        for (int s = seg + 1; s < 32; ++s) rA += csa[(b * 32 + s) * 128 + co];
        if (seg == 31) SA[((size_t)b * 1025 + 1024) * 128 + co] = 0.f;
        for (int jj = 31; jj >= 0; --jj) {
            rA += gs[jj * 128 + co];
            SA[((size_t)b * 1025 + seg * 32 + jj) * 128 + co] = rA;
        }
    } else {
        float rB = 0.f;
        for (int s = seg + 1; s < 32; ++s) rB += csb[(b * 32 + s) * 128 + co];
        if (seg == 31) SB[((size_t)b * 1025 + 1024) * 128 + co] = 0.f;
        for (int jj = 31; jj >= 0; --jj) {
            rB += pl[jj] * gs[jj * 128 + co];
            SB[((size_t)b * 1025 + seg * 32 + jj) * 128 + co] = rB;
        }
    }
}

// ---------------------------------------------------------------------------
// K6: out[b][co][n] = ((t[n]*SA[k(n)][co] + SB[k(n)][co])/M)*sc[co] + bs[co] + x
// ---------------------------------------------------------------------------
__global__ __launch_bounds__(256) void k_final(
    const float* __restrict__ x, const float* __restrict__ t,
    const float* __restrict__ ps, const float* __restrict__ SA, const float* __restrict__ SB,
    const float* __restrict__ b2, const float* __restrict__ gamma, const float* __restrict__ beta,
    const float* __restrict__ mean, const float* __restrict__ var,
    float* __restrict__ out)
{
    const int nt = blockIdx.x;
    const int b = blockIdx.y;
    const int tid = threadIdx.x;
    const int n0 = nt * 128;
    __shared__ float psl[1024];
    __shared__ float tl[128];
    __shared__ int   kl[128];
    __shared__ float sc[128], bs[128];
    __shared__ float sa_s[32][129], sb_s[32][129];

    for (int it = 0; it < 4; ++it) psl[tid + 256 * it] = ps[b * 1024 + tid + 256 * it];
    __syncthreads();
    if (tid < 128) {
        float tv = t[(size_t)b * Nn + n0 + tid];
        tl[tid] = tv;
        float key = -tv;
        int lo = 0, hi = 1024;
        while (lo < hi) { int mid = (lo + hi) >> 1; if (psl[mid] > key) hi = mid; else lo = mid + 1; }
        kl[tid] = lo;
    } else {
        int co = tid - 128;
        float s = gamma[co] * rsqrtf(var[co] + 1e-5f);
        sc[co] = s;
        bs[co] = (b2[co] - mean[co]) * s + beta[co];
    }
    __syncthreads();

    const float invM = 1.0f / 1024.0f;
    for (int sub = 0; sub < 4; ++sub) {
        for (int it = 0; it < 16; ++it) {
            int f = tid + 256 * it;
            int rowl = f >> 7, co = f & 127;
            int k = kl[sub * 32 + rowl];
            sa_s[rowl][co] = SA[((size_t)b * 1025 + k) * 128 + co];
            sb_s[rowl][co] = SB[((size_t)b * 1025 + k) * 128 + co];
        }
        __syncthreads();
        for (int it = 0; it < 4; ++it) {
            int f = tid + 256 * it;
            int co = f >> 3, nn0 = (f & 7) * 4;
            size_t gidx = ((size_t)b * Cn + co) * Nn + n0 + sub * 32 + nn0;
            float4 xv = *(const float4*)&x[gidx];
            float scv = sc[co], bsv = bs[co];
            float4 o;
            float v0 = (tl[sub*32+nn0+0] * sa_s[nn0+0][co] + sb_s[nn0+0][co]) * invM;
            float v1 = (tl[sub*32+nn0+1] * sa_s[nn0+1][co] + sb_s[nn0+1][co]) * invM;
            float v2 = (tl[sub*32+nn0+2] * sa_s[nn0+2][co] + sb_s[nn0+2][co]) * invM;
            float v3 = (tl[sub*32+nn0+3] * sa_s[nn0+3][co] + sb_s[nn0+3][co]) * invM;
            o.x = v0 * scv + bsv + xv.x;
            o.y = v1 * scv + bsv + xv.y;
            o.z = v2 * scv + bsv + xv.z;
            o.w = v3 * scv + bsv + xv.w;
            *(float4*)&out[gidx] = o;
        }
        __syncthreads();
    }
}

// ---------------------------------------------------------------------------
extern "C" void kernel_launch(void* const* d_in, const int* in_sizes, int n_in,
                              void* d_out, int out_size, void* d_ws, size_t ws_size,
                              hipStream_t stream)
{
    const float* x  = (const float*)d_in[0];
    const float* w1 = (const float*)d_in[1];
    const float* b1 = (const float*)d_in[2];
    const float* w3 = (const float*)d_in[3];
    const float* b3 = (const float*)d_in[4];
    const float* w4 = (const float*)d_in[5];
    const float* b4 = (const float*)d_in[6];
    const float* w5 = (const float*)d_in[7];
    const float* w2 = (const float*)d_in[8];
    const float* b2 = (const float*)d_in[9];
    const float* gm = (const float*)d_in[10];
    const float* bt = (const float*)d_in[11];
    const float* mn = (const float*)d_in[12];
    const float* vr = (const float*)d_in[13];
    float* out = (float*)d_out;

    float* ws = (float*)d_ws;
    const size_t FTOT = 3823872;           // floats (~15.3 MB)
    if (ws_size < FTOT * sizeof(float)) return;

    float* t_w  = ws;                      // 32768
    float* p_w  = ws + 32768;              // 8192
    float* ps_w = ws + 40960;              // 8192
    int*   pm_w = (int*)(ws + 49152);      // 8192
    float* g_w  = ws + 581632;             // 1048576
    float* csa  = ws + 1630208;            // 32768
    float* csb  = ws + 1662976;            // 32768
    float* SAp  = ws + 1695744;            // 1049600
    float* SBp  = ws + 2745344;            // 1049600
    float* ucon = ws + 3811328;            // 256
    u16*   w1b  = (u16*)(ws + 3811584);    // 8192 u16 = 4096 fl
    u16*   w4b  = (u16*)(ws + 3815680);    // 8192 u16
    u16*   w2b  = (u16*)(ws + 3819776);    // 8192 u16

    k_pre  <<<9,           256, 0, stream>>>(w1, w4, w2, w3, b3, w5, w1b, w4b, w2b, ucon);
    k_conv <<<dim3(64, 8), 256, 0, stream>>>(x, b1, b4, w1b, w4b, ucon, w2b, t_w, p_w, g_w);
    k_rank <<<dim3(8, 8),  128, 0, stream>>>(p_w, ps_w, pm_w);
    k_scanA<<<dim3(32, 8), 256, 0, stream>>>(g_w, ps_w, pm_w, csa, csb);
    k_scanC<<<dim3(32, 8), 256, 0, stream>>>(g_w, ps_w, pm_w, csa, csb, SAp, SBp);
    k_final<<<dim3(32, 8), 256, 0, stream>>>(x, t_w, ps_w, SAp, SBp, b2, gm, bt, mn, vr, out);
}